// Round 1
// baseline (316.139 us; speedup 1.0000x reference)
//
#include <hip/hip_runtime.h>

// ---------------------------------------------------------------------------
// AttentionBlock: out = softmax((xWq^T)(xWk^T)^T / sqrt(512)) (xWv^T)
// x: [8,2048,512] f32; Wq/Wk/Wv: [512,512] f32; out: [8,2048,512] f32
// Pipeline: fp32->bf16 convert | 3x NT MFMA GEMM (V written transposed) |
//           fused flash attention (online softmax, K/V LDS-staged, Q in regs)
// Workspace: 68.7 MB.
// ---------------------------------------------------------------------------

typedef __bf16 bf16x8 __attribute__((ext_vector_type(8)));
typedef __bf16 bf16x4 __attribute__((ext_vector_type(4)));
typedef float  f32x4  __attribute__((ext_vector_type(4)));

constexpr int SEQ = 2048;
constexpr int DM  = 512;
constexpr int NB  = 8;
constexpr int GS  = NB * SEQ;    // 16384

__device__ __forceinline__ void gl16(const void* g, void* l) {
  __builtin_amdgcn_global_load_lds((const __attribute__((address_space(1))) void*)g,
                                   (__attribute__((address_space(3))) void*)l, 16, 0, 0);
}

__device__ __forceinline__ f32x4 mfma16(bf16x8 a, bf16x8 b, f32x4 c) {
  return __builtin_amdgcn_mfma_f32_16x16x32_bf16(a, b, c, 0, 0, 0);
}

// ---------------------------------------------------------------------------
// Kernel 0: fp32 -> bf16 conversion (x + 3 weights), float4 vectorized
// ---------------------------------------------------------------------------
__global__ void convert_kernel(const float* __restrict__ x,
                               const float* __restrict__ wq,
                               const float* __restrict__ wk,
                               const float* __restrict__ wv,
                               __bf16* __restrict__ xb,
                               __bf16* __restrict__ wqb,
                               __bf16* __restrict__ wkb,
                               __bf16* __restrict__ wvb) {
  const int NX4 = (GS * DM) / 4;   // 2,097,152
  const int NW4 = (DM * DM) / 4;   // 65,536
  const int stride = gridDim.x * blockDim.x;
  const int tid = blockIdx.x * blockDim.x + threadIdx.x;
  for (int i = tid; i < NX4; i += stride) {
    float4 v = ((const float4*)x)[i];
    bf16x4 o = { (__bf16)v.x, (__bf16)v.y, (__bf16)v.z, (__bf16)v.w };
    ((bf16x4*)xb)[i] = o;
  }
  for (int i = tid; i < NW4; i += stride) {
    float4 v = ((const float4*)wq)[i];
    bf16x4 o = { (__bf16)v.x, (__bf16)v.y, (__bf16)v.z, (__bf16)v.w };
    ((bf16x4*)wqb)[i] = o;
  }
  for (int i = tid; i < NW4; i += stride) {
    float4 v = ((const float4*)wk)[i];
    bf16x4 o = { (__bf16)v.x, (__bf16)v.y, (__bf16)v.z, (__bf16)v.w };
    ((bf16x4*)wkb)[i] = o;
  }
  for (int i = tid; i < NW4; i += stride) {
    float4 v = ((const float4*)wv)[i];
    bf16x4 o = { (__bf16)v.x, (__bf16)v.y, (__bf16)v.z, (__bf16)v.w };
    ((bf16x4*)wvb)[i] = o;
  }
}

// ---------------------------------------------------------------------------
// Kernel 1: NT GEMM  C[M][N] = A[M][512] * B[N][512]^T   (bf16 in, bf16 out)
// m97 structure: 128x128 tile, BK=32, 4 waves (each 64x64), global_load_lds.
// ---------------------------------------------------------------------------
__global__ __launch_bounds__(256, 2) void gemm_nt_kernel(
    const __bf16* __restrict__ A, const __bf16* __restrict__ Bm,
    __bf16* __restrict__ C, int N) {
  __shared__ __bf16 As[128 * 32];
  __shared__ __bf16 Bs[128 * 32];
  const int t = threadIdx.x;
  const int w = t >> 6, l = t & 63;
  const int l15 = l & 15, lg = l >> 4;
  const int m0 = blockIdx.x * 128, n0 = blockIdx.y * 128;
  const int wr = w >> 1, wc = w & 1;

  f32x4 acc[4][4] = {};
  const char* Ab = (const char*)A + (size_t)m0 * (DM * 2);
  const char* Bb = (const char*)Bm + (size_t)n0 * (DM * 2);

  for (int k0 = 0; k0 < DM; k0 += 32) {
#pragma unroll
    for (int i = 0; i < 2; ++i) {
      const int f = (i * 256 + t) * 16;
      const int row = f >> 6, c = f & 63;
      gl16(Ab + (size_t)row * (DM * 2) + k0 * 2 + c, (char*)As + f);
      gl16(Bb + (size_t)row * (DM * 2) + k0 * 2 + c, (char*)Bs + f);
    }
    __syncthreads();
    bf16x8 af[4], bfr[4];
#pragma unroll
    for (int mi = 0; mi < 4; ++mi)
      af[mi] = *(const bf16x8*)((const char*)As + (wr * 64 + mi * 16 + l15) * 64 + lg * 16);
#pragma unroll
    for (int ni = 0; ni < 4; ++ni)
      bfr[ni] = *(const bf16x8*)((const char*)Bs + (wc * 64 + ni * 16 + l15) * 64 + lg * 16);
#pragma unroll
    for (int mi = 0; mi < 4; ++mi)
#pragma unroll
      for (int ni = 0; ni < 4; ++ni)
        acc[mi][ni] = mfma16(af[mi], bfr[ni], acc[mi][ni]);
    __syncthreads();
  }
  // C/D layout: col = lane&15, row = (lane>>4)*4 + r  [m89-verified]
#pragma unroll
  for (int mi = 0; mi < 4; ++mi)
#pragma unroll
    for (int ni = 0; ni < 4; ++ni)
#pragma unroll
      for (int r = 0; r < 4; ++r) {
        const int row = m0 + wr * 64 + mi * 16 + lg * 4 + r;
        const int col = n0 + wc * 64 + ni * 16 + l15;
        C[(size_t)row * N + col] = (__bf16)acc[mi][ni][r];
      }
}

// ---------------------------------------------------------------------------
// Kernel 2: fused flash attention.
// Grid (32,8) = (q-tile, batch); 512 threads (8 waves); QBLK=64, KVBLK=64.
// QK^T roles: wave w -> qi2=w>>2 (32 q rows), kvq=w&3 (16 kv cols); Q in regs.
// PV roles:   wave w -> e columns [w*64, w*64+64), all 64 q rows.
// LDS: Ks[64][512] (rows XOR-swizzled), Vs[512][64] (Vt rows, XOR-swizzled),
//      Ss[64][68] f32 scores, Ps[64][72] bf16 probs, row stats. ~158 KB.
// ---------------------------------------------------------------------------
constexpr int NT = SEQ / 64;   // 32 kv tiles

__global__ __launch_bounds__(512, 2) void attn_kernel(
    const __bf16* __restrict__ Qg, const __bf16* __restrict__ Kg,
    const __bf16* __restrict__ Vt, float* __restrict__ Out) {
  __shared__ __bf16 Ks[64 * 512];
  __shared__ __bf16 Vs[512 * 64];
  __shared__ float  Ss[64 * 68];
  __shared__ __bf16 Ps[64 * 72];
  __shared__ float  m_s[64], l_s[64], corr_s[64];
  __shared__ int    flags_s[8];

  const int t = threadIdx.x;
  const int w = t >> 6, l = t & 63;
  const int l15 = l & 15, lg = l >> 4;
  const int b = blockIdx.y;
  const int q0 = blockIdx.x * 64;
  const int qi2 = w >> 2, kvq = w & 3;

  // Q fragments: rows q0 + qi2*32 + mi*16 + l15, k = ks*32 + lg*8 .. +8
  bf16x8 qf[2][16];
  {
    const char* Qb = (const char*)Qg +
        ((size_t)(b * SEQ + q0 + qi2 * 32 + l15) * DM) * 2 + lg * 16;
#pragma unroll
    for (int mi = 0; mi < 2; ++mi)
#pragma unroll
      for (int ks = 0; ks < 16; ++ks)
        qf[mi][ks] = *(const bf16x8*)(Qb + (size_t)mi * 16 * DM * 2 + ks * 64);
  }

  f32x4 o[4][4] = {};

  if (t < 64) { m_s[t] = -__builtin_inff(); l_s[t] = 0.f; }

  const char* Kb = (const char*)Kg + (size_t)b * SEQ * DM * 2;  // rows = 1024B
  const char* Vb = (const char*)Vt + (size_t)b * SEQ * 2;       // Vt[e][b*SEQ+s], row = 32768B

  // prologue: stage K tile 0 (source pre-swizzled so linear LDS dest + swz read match)
#pragma unroll
  for (int i = 0; i < 8; ++i) {
    const int f = (i * 512 + t) * 16;
    const int row = f >> 10, c = f & 1023;
    const int sc = c ^ ((row & 7) << 4);
    gl16(Kb + (size_t)row * 1024 + sc, (char*)Ks + f);
  }
  __syncthreads();

  const float SCL = 0.0637639022f;  // log2(e)/sqrt(512): softmax in exp2 domain

  for (int it = 0; it < NT; ++it) {
    const int kv0 = it * 64;

    // ---- phase A: issue V-stage (drains at next barrier), then QK^T ----
#pragma unroll
    for (int i = 0; i < 8; ++i) {
      const int f = (i * 512 + t) * 16;
      const int e = f >> 7, c2 = f & 127;
      const int sc2 = c2 ^ ((e & 7) << 4);
      gl16(Vb + (size_t)e * (GS * 2) + (size_t)kv0 * 2 + sc2, (char*)Vs + f);
    }
    {
      f32x4 sa0 = {}, sa1 = {};
      const int krow = kvq * 16 + l15;
      const char* KsR = (const char*)Ks + krow * 1024;
      const int ksw = (krow & 7) << 4;
#pragma unroll
      for (int ks = 0; ks < 16; ++ks) {
        bf16x8 kf = *(const bf16x8*)(KsR + ((ks * 64 + lg * 16) ^ ksw));
        sa0 = mfma16(qf[0][ks], kf, sa0);
        sa1 = mfma16(qf[1][ks], kf, sa1);
      }
#pragma unroll
      for (int r = 0; r < 4; ++r) {
        Ss[(qi2 * 32 + lg * 4 + r) * 68 + kvq * 16 + l15] = sa0[r] * SCL;
        Ss[(qi2 * 32 + 16 + lg * 4 + r) * 68 + kvq * 16 + l15] = sa1[r] * SCL;
      }
    }
    __syncthreads();

    // ---- phase B: online softmax, 8 threads per row ----
    {
      const int row = w * 8 + (l >> 3), c8 = l & 7;
      const float* Sr = &Ss[row * 68 + c8 * 8];
      float4 v0 = *(const float4*)(Sr);
      float4 v1 = *(const float4*)(Sr + 4);
      float tmax = fmaxf(fmaxf(fmaxf(v0.x, v0.y), fmaxf(v0.z, v0.w)),
                         fmaxf(fmaxf(v1.x, v1.y), fmaxf(v1.z, v1.w)));
      tmax = fmaxf(tmax, __shfl_xor(tmax, 1));
      tmax = fmaxf(tmax, __shfl_xor(tmax, 2));
      tmax = fmaxf(tmax, __shfl_xor(tmax, 4));
      const float mold = m_s[row];
      const float mnew = fmaxf(mold, tmax);
      const float corr = exp2f(mold - mnew);   // == 1.0f exactly when no new max
      const float p0 = exp2f(v0.x - mnew), p1 = exp2f(v0.y - mnew);
      const float p2 = exp2f(v0.z - mnew), p3 = exp2f(v0.w - mnew);
      const float p4 = exp2f(v1.x - mnew), p5 = exp2f(v1.y - mnew);
      const float p6 = exp2f(v1.z - mnew), p7 = exp2f(v1.w - mnew);
      float rsum = ((p0 + p1) + (p2 + p3)) + ((p4 + p5) + (p6 + p7));
      rsum += __shfl_xor(rsum, 1);
      rsum += __shfl_xor(rsum, 2);
      rsum += __shfl_xor(rsum, 4);
      const float lnew = l_s[row] * corr + rsum;
      if (c8 == 0) { m_s[row] = mnew; l_s[row] = lnew; corr_s[row] = corr; }
      const int allskip = __all(corr == 1.0f);
      if (l == 0) flags_s[w] = allskip;
      bf16x8 pb = { (__bf16)p0, (__bf16)p1, (__bf16)p2, (__bf16)p3,
                    (__bf16)p4, (__bf16)p5, (__bf16)p6, (__bf16)p7 };
      *(bf16x8*)((char*)Ps + row * 144 + c8 * 16) = pb;
    }
    __syncthreads();

    // ---- phase C: issue next-K stage (drains at loop-end barrier), rescale, PV ----
    {
      const int kvn = ((it + 1) == NT ? 0 : (it + 1)) * 64;
#pragma unroll
      for (int i = 0; i < 8; ++i) {
        const int f = (i * 512 + t) * 16;
        const int row = f >> 10, c = f & 1023;
        const int sc = c ^ ((row & 7) << 4);
        gl16(Kb + (size_t)(kvn + row) * 1024 + sc, (char*)Ks + f);
      }
      const int flag = flags_s[l & 7];
      if (!__all(flag != 0)) {
#pragma unroll
        for (int mi = 0; mi < 4; ++mi) {
          float cr[4];
#pragma unroll
          for (int r = 0; r < 4; ++r) cr[r] = corr_s[mi * 16 + lg * 4 + r];
#pragma unroll
          for (int ni = 0; ni < 4; ++ni)
#pragma unroll
            for (int r = 0; r < 4; ++r) o[mi][ni][r] *= cr[r];
        }
      }
#pragma unroll
      for (int ks = 0; ks < 2; ++ks) {
        bf16x8 pf[4];
#pragma unroll
        for (int mi = 0; mi < 4; ++mi)
          pf[mi] = *(const bf16x8*)((const char*)Ps + (mi * 16 + l15) * 144 + ks * 64 + lg * 16);
#pragma unroll
        for (int ni = 0; ni < 4; ++ni) {
          const int er = w * 64 + ni * 16 + l15;
          bf16x8 vf = *(const bf16x8*)((const char*)Vs + er * 128 +
                                       ((ks * 64 + lg * 16) ^ ((er & 7) << 4)));
#pragma unroll
          for (int mi = 0; mi < 4; ++mi)
            o[mi][ni] = mfma16(pf[mi], vf, o[mi][ni]);
        }
      }
    }
    __syncthreads();
  }

  // ---- epilogue: normalize by l, write fp32 ----
#pragma unroll
  for (int mi = 0; mi < 4; ++mi) {
    float rl[4];
#pragma unroll
    for (int r = 0; r < 4; ++r) rl[r] = 1.0f / l_s[mi * 16 + lg * 4 + r];
#pragma unroll
    for (int ni = 0; ni < 4; ++ni)
#pragma unroll
      for (int r = 0; r < 4; ++r) {
        const int row = q0 + mi * 16 + lg * 4 + r;
        const int col = w * 64 + ni * 16 + l15;
        Out[((size_t)b * SEQ + row) * DM + col] = o[mi][ni][r] * rl[r];
      }
  }
}

// ---------------------------------------------------------------------------
// Launcher. Workspace layout (bytes):
//   xb 0..16M | wqb/wkb/wvb | Qg | Kg | Vt   (total 68,681,728 B)
// ---------------------------------------------------------------------------
extern "C" void kernel_launch(void* const* d_in, const int* in_sizes, int n_in,
                              void* d_out, int out_size, void* d_ws, size_t ws_size,
                              hipStream_t stream) {
  const float* x  = (const float*)d_in[0];
  const float* wq = (const float*)d_in[1];
  const float* wk = (const float*)d_in[2];
  const float* wv = (const float*)d_in[3];
  float* out = (float*)d_out;
  char* ws = (char*)d_ws;

  __bf16* xb  = (__bf16*)(ws);
  __bf16* wqb = (__bf16*)(ws + 16777216);
  __bf16* wkb = (__bf16*)(ws + 17301504);
  __bf16* wvb = (__bf16*)(ws + 17825792);
  __bf16* Qg  = (__bf16*)(ws + 18350080);
  __bf16* Kg  = (__bf16*)(ws + 35127296);
  __bf16* Vt  = (__bf16*)(ws + 51904512);

  convert_kernel<<<2048, 256, 0, stream>>>(x, wq, wk, wv, xb, wqb, wkb, wvb);
  // Q = x * Wq^T : [16384x512] = [16384x512]*[512x512]^T
  gemm_nt_kernel<<<dim3(GS / 128, DM / 128), 256, 0, stream>>>(xb, wqb, Qg, DM);
  // K = x * Wk^T
  gemm_nt_kernel<<<dim3(GS / 128, DM / 128), 256, 0, stream>>>(xb, wkb, Kg, DM);
  // Vt[e][gs] = Wv * x^T : [512x16384] (V stored transposed, no scatter)
  gemm_nt_kernel<<<dim3(DM / 128, GS / 128), 256, 0, stream>>>(wvb, xb, Vt, GS);
  // fused attention
  attn_kernel<<<dim3(SEQ / 64, NB), 512, 0, stream>>>(Qg, Kg, Vt, out);
}

// Round 2
// 273.303 us; speedup vs baseline: 1.1567x; 1.1567x over previous
//
#include <hip/hip_runtime.h>

// ---------------------------------------------------------------------------
// AttentionBlock: out = softmax((xWq^T)(xWk^T)^T / sqrt(512)) (xWv^T)
// R1: attn restructured for 2 blocks/CU (256 thr, QBLK=32, KVBLK=32, LDS 72KB),
//     XCD-aware batch swizzle (K/V L2-resident per XCD), Q+K GEMM fused.
// ---------------------------------------------------------------------------

typedef __bf16 bf16x8 __attribute__((ext_vector_type(8)));
typedef __bf16 bf16x4 __attribute__((ext_vector_type(4)));
typedef float  f32x4  __attribute__((ext_vector_type(4)));

constexpr int SEQ = 2048;
constexpr int DM  = 512;
constexpr int NB  = 8;
constexpr int GS  = NB * SEQ;    // 16384
constexpr int NT2 = SEQ / 32;    // 64 kv tiles of 32

__device__ __forceinline__ void gl16(const void* g, void* l) {
  __builtin_amdgcn_global_load_lds((const __attribute__((address_space(1))) void*)g,
                                   (__attribute__((address_space(3))) void*)l, 16, 0, 0);
}

__device__ __forceinline__ f32x4 mfma16(bf16x8 a, bf16x8 b, f32x4 c) {
  return __builtin_amdgcn_mfma_f32_16x16x32_bf16(a, b, c, 0, 0, 0);
}

// ---------------------------------------------------------------------------
// Kernel 0: fp32 -> bf16 conversion (x + 3 weights), float4 vectorized
// ---------------------------------------------------------------------------
__global__ void convert_kernel(const float* __restrict__ x,
                               const float* __restrict__ wq,
                               const float* __restrict__ wk,
                               const float* __restrict__ wv,
                               __bf16* __restrict__ xb,
                               __bf16* __restrict__ wqb,
                               __bf16* __restrict__ wkb,
                               __bf16* __restrict__ wvb) {
  const int NX4 = (GS * DM) / 4;
  const int NW4 = (DM * DM) / 4;
  const int stride = gridDim.x * blockDim.x;
  const int tid = blockIdx.x * blockDim.x + threadIdx.x;
  for (int i = tid; i < NX4; i += stride) {
    float4 v = ((const float4*)x)[i];
    bf16x4 o = { (__bf16)v.x, (__bf16)v.y, (__bf16)v.z, (__bf16)v.w };
    ((bf16x4*)xb)[i] = o;
  }
  for (int i = tid; i < NW4; i += stride) {
    float4 v = ((const float4*)wq)[i];
    bf16x4 o = { (__bf16)v.x, (__bf16)v.y, (__bf16)v.z, (__bf16)v.w };
    ((bf16x4*)wqb)[i] = o;
  }
  for (int i = tid; i < NW4; i += stride) {
    float4 v = ((const float4*)wk)[i];
    bf16x4 o = { (__bf16)v.x, (__bf16)v.y, (__bf16)v.z, (__bf16)v.w };
    ((bf16x4*)wkb)[i] = o;
  }
  for (int i = tid; i < NW4; i += stride) {
    float4 v = ((const float4*)wv)[i];
    bf16x4 o = { (__bf16)v.x, (__bf16)v.y, (__bf16)v.z, (__bf16)v.w };
    ((bf16x4*)wvb)[i] = o;
  }
}

// ---------------------------------------------------------------------------
// Kernel 1: NT GEMM  C[M][N] = A[M][512] * B[N][512]^T   (bf16 in, bf16 out)
// 128x128 tile, BK=32, 4 waves, global_load_lds width=16.
// ---------------------------------------------------------------------------
__global__ __launch_bounds__(256, 2) void gemm_nt_kernel(
    const __bf16* __restrict__ A, const __bf16* __restrict__ Bm,
    __bf16* __restrict__ C, int N) {
  __shared__ __bf16 As[128 * 32];
  __shared__ __bf16 Bs[128 * 32];
  const int t = threadIdx.x;
  const int w = t >> 6, l = t & 63;
  const int l15 = l & 15, lg = l >> 4;
  const int m0 = blockIdx.x * 128, n0 = blockIdx.y * 128;
  const int wr = w >> 1, wc = w & 1;

  f32x4 acc[4][4] = {};
  const char* Ab = (const char*)A + (size_t)m0 * (DM * 2);
  const char* Bb = (const char*)Bm + (size_t)n0 * (DM * 2);

  for (int k0 = 0; k0 < DM; k0 += 32) {
#pragma unroll
    for (int i = 0; i < 2; ++i) {
      const int f = (i * 256 + t) * 16;
      const int row = f >> 6, c = f & 63;
      gl16(Ab + (size_t)row * (DM * 2) + k0 * 2 + c, (char*)As + f);
      gl16(Bb + (size_t)row * (DM * 2) + k0 * 2 + c, (char*)Bs + f);
    }
    __syncthreads();
    bf16x8 af[4], bfr[4];
#pragma unroll
    for (int mi = 0; mi < 4; ++mi)
      af[mi] = *(const bf16x8*)((const char*)As + (wr * 64 + mi * 16 + l15) * 64 + lg * 16);
#pragma unroll
    for (int ni = 0; ni < 4; ++ni)
      bfr[ni] = *(const bf16x8*)((const char*)Bs + (wc * 64 + ni * 16 + l15) * 64 + lg * 16);
#pragma unroll
    for (int mi = 0; mi < 4; ++mi)
#pragma unroll
      for (int ni = 0; ni < 4; ++ni)
        acc[mi][ni] = mfma16(af[mi], bfr[ni], acc[mi][ni]);
    __syncthreads();
  }
#pragma unroll
  for (int mi = 0; mi < 4; ++mi)
#pragma unroll
    for (int ni = 0; ni < 4; ++ni)
#pragma unroll
      for (int r = 0; r < 4; ++r) {
        const int row = m0 + wr * 64 + mi * 16 + lg * 4 + r;
        const int col = n0 + wc * 64 + ni * 16 + l15;
        C[(size_t)row * N + col] = (__bf16)acc[mi][ni][r];
      }
}

// ---------------------------------------------------------------------------
// Kernel 2: fused flash attention.
// Grid: 512 blocks 1D; b = bid&7 (XCD-matched: one batch per XCD -> K/V L2-
// resident), q0 = (bid>>3)*32. 256 threads (4 waves), KVBLK=32.
// QK^T roles: wave w -> qi=w>>1 (16 q rows), kj=w&1 (16 kv cols); Q in regs.
// PV roles:   wave w -> e columns [w*128, w*128+128).
// QK layout: fused [16384][1024] bf16, Q = cols 0..511, K = cols 512..1023.
// LDS ~72.6 KB -> 2 blocks/CU.
// ---------------------------------------------------------------------------
__global__ __launch_bounds__(256, 2) void attn_kernel(
    const __bf16* __restrict__ QK, const __bf16* __restrict__ Vt,
    float* __restrict__ Out) {
  __shared__ __bf16 Ks[32 * 512];   // rows 1024B, 16B-slot XOR swizzle (row&7)<<4
  __shared__ __bf16 Vs[512 * 32];   // Vt rows: [e][kv32], 64B rows, XOR (e&3)<<4
  __shared__ float  Ss[32 * 36];
  __shared__ __bf16 Ps[32 * 32];    // 64B rows, XOR (row&3)<<4
  __shared__ float  m_s[32], l_s[32], corr_s[32];
  __shared__ int    flags_s[4];

  const int t = threadIdx.x;
  const int w = t >> 6, l = t & 63;
  const int l15 = l & 15, lg = l >> 4;
  const int bid = blockIdx.x;
  const int b = bid & 7;            // batch == XCD
  const int q0 = (bid >> 3) * 32;
  const int qi = w >> 1, kj = w & 1;

  // Q fragments: 16 rows per wave (q0 + qi*16 + l15), full D=512 -> 64 VGPR
  bf16x8 qf[16];
  {
    const char* Qb = (const char*)QK +
        (size_t)(b * SEQ + q0 + qi * 16 + l15) * 2048 + lg * 16;
#pragma unroll
    for (int ks = 0; ks < 16; ++ks)
      qf[ks] = *(const bf16x8*)(Qb + ks * 64);
  }

  f32x4 o[2][8] = {};
  if (t < 32) { m_s[t] = -__builtin_inff(); l_s[t] = 0.f; }

  const char* Kb = (const char*)QK + (size_t)b * SEQ * 2048 + 1024;  // K cols
  const char* Vb = (const char*)Vt + (size_t)b * SEQ * 2;            // Vt[e][b*SEQ+s]

  // prologue: stage K tile 0 (pre-swizzled source, linear LDS dest)
#pragma unroll
  for (int i = 0; i < 8; ++i) {
    const int f = (i * 256 + t) * 16;
    const int row = f >> 10, c = f & 1023;
    gl16(Kb + (size_t)row * 2048 + (c ^ ((row & 7) << 4)), (char*)Ks + f);
  }
  __syncthreads();

  const float SCL = 0.0637639022f;  // log2(e)/sqrt(512)

  for (int it = 0; it < NT2; ++it) {
    const int kv0 = it * 32;

    // ---- phase A: issue V-stage (drains at barrier A), QK^T ----
#pragma unroll
    for (int i = 0; i < 8; ++i) {
      const int f = (i * 256 + t) * 16;
      const int e = f >> 6, c2 = f & 63;
      gl16(Vb + (size_t)e * (GS * 2) + (size_t)kv0 * 2 + (c2 ^ ((e & 3) << 4)),
           (char*)Vs + f);
    }
    {
      f32x4 sa = {};
      const int krow = kj * 16 + l15;
      const char* KsR = (const char*)Ks + krow * 1024;
      const int ksw = (krow & 7) << 4;
#pragma unroll
      for (int ks = 0; ks < 16; ++ks) {
        bf16x8 kf = *(const bf16x8*)(KsR + ((ks * 64 + lg * 16) ^ ksw));
        sa = mfma16(qf[ks], kf, sa);
      }
#pragma unroll
      for (int r = 0; r < 4; ++r)
        Ss[(qi * 16 + lg * 4 + r) * 36 + kj * 16 + l15] = sa[r] * SCL;
    }
    __syncthreads();

    // ---- phase B: online softmax, 8 threads per row, 4 scores each ----
    {
      const int row = t >> 3, c8 = t & 7;
      float4 v0 = *(const float4*)&Ss[row * 36 + c8 * 4];
      float tmax = fmaxf(fmaxf(v0.x, v0.y), fmaxf(v0.z, v0.w));
      tmax = fmaxf(tmax, __shfl_xor(tmax, 1));
      tmax = fmaxf(tmax, __shfl_xor(tmax, 2));
      tmax = fmaxf(tmax, __shfl_xor(tmax, 4));
      const float mold = m_s[row];
      const float mnew = fmaxf(mold, tmax);
      const float corr = exp2f(mold - mnew);   // exactly 1.0f when no new max
      const float p0 = exp2f(v0.x - mnew), p1 = exp2f(v0.y - mnew);
      const float p2 = exp2f(v0.z - mnew), p3 = exp2f(v0.w - mnew);
      float rsum = (p0 + p1) + (p2 + p3);
      rsum += __shfl_xor(rsum, 1);
      rsum += __shfl_xor(rsum, 2);
      rsum += __shfl_xor(rsum, 4);
      if (c8 == 0) { m_s[row] = mnew; l_s[row] = l_s[row] * corr + rsum; corr_s[row] = corr; }
      const int allskip = __all(corr == 1.0f);
      if (l == 0) flags_s[w] = allskip;
      bf16x4 pb = { (__bf16)p0, (__bf16)p1, (__bf16)p2, (__bf16)p3 };
      *(bf16x4*)((char*)Ps + row * 64 + (((c8 >> 1) * 16) ^ ((row & 3) << 4)) +
                 (c8 & 1) * 8) = pb;
    }
    __syncthreads();

    // ---- phase C: issue next-K stage (drains at loop-end barrier), rescale, PV ----
    {
      const int kvn = ((it + 1) == NT2 ? 0 : (it + 1)) * 32;
#pragma unroll
      for (int i = 0; i < 8; ++i) {
        const int f = (i * 256 + t) * 16;
        const int row = f >> 10, c = f & 1023;
        gl16(Kb + (size_t)(kvn + row) * 2048 + (c ^ ((row & 7) << 4)), (char*)Ks + f);
      }
      const int fl = flags_s[0] & flags_s[1] & flags_s[2] & flags_s[3];
      if (!fl) {
#pragma unroll
        for (int mi = 0; mi < 2; ++mi) {
          float cr[4];
#pragma unroll
          for (int r = 0; r < 4; ++r) cr[r] = corr_s[mi * 16 + lg * 4 + r];
#pragma unroll
          for (int ni = 0; ni < 8; ++ni)
#pragma unroll
            for (int r = 0; r < 4; ++r) o[mi][ni][r] *= cr[r];
        }
      }
      bf16x8 pf[2];
#pragma unroll
      for (int mi = 0; mi < 2; ++mi) {
        const int prow = mi * 16 + l15;
        pf[mi] = *(const bf16x8*)((const char*)Ps + prow * 64 +
                                  ((lg * 16) ^ ((prow & 3) << 4)));
      }
#pragma unroll
      for (int ni = 0; ni < 8; ++ni) {
        const int er = w * 128 + ni * 16 + l15;
        bf16x8 vf = *(const bf16x8*)((const char*)Vs + er * 64 +
                                     ((lg * 16) ^ ((er & 3) << 4)));
#pragma unroll
        for (int mi = 0; mi < 2; ++mi)
          o[mi][ni] = mfma16(pf[mi], vf, o[mi][ni]);
      }
    }
    __syncthreads();
  }

  // ---- epilogue: normalize, write fp32 ----
#pragma unroll
  for (int mi = 0; mi < 2; ++mi) {
    float rl[4];
#pragma unroll
    for (int r = 0; r < 4; ++r) rl[r] = 1.0f / l_s[mi * 16 + lg * 4 + r];
#pragma unroll
    for (int ni = 0; ni < 8; ++ni)
#pragma unroll
      for (int r = 0; r < 4; ++r) {
        const int row = q0 + mi * 16 + lg * 4 + r;
        const int col = w * 128 + ni * 16 + l15;
        Out[((size_t)b * SEQ + row) * DM + col] = o[mi][ni][r] * rl[r];
      }
  }
}

// ---------------------------------------------------------------------------
// Launcher. Workspace (bytes, total 68,681,728):
//   xb 0 | wqkb 16777216 (Wq;Wk contiguous) | wvb 17825792 | qk 18350080
//   ([16384][1024]: Q cols 0..511, K cols 512..1023) | vt 51904512
// ---------------------------------------------------------------------------
extern "C" void kernel_launch(void* const* d_in, const int* in_sizes, int n_in,
                              void* d_out, int out_size, void* d_ws, size_t ws_size,
                              hipStream_t stream) {
  const float* x  = (const float*)d_in[0];
  const float* wq = (const float*)d_in[1];
  const float* wk = (const float*)d_in[2];
  const float* wv = (const float*)d_in[3];
  float* out = (float*)d_out;
  char* ws = (char*)d_ws;

  __bf16* xb   = (__bf16*)(ws);
  __bf16* wqkb = (__bf16*)(ws + 16777216);
  __bf16* wvb  = (__bf16*)(ws + 17825792);
  __bf16* qk   = (__bf16*)(ws + 18350080);
  __bf16* vt   = (__bf16*)(ws + 51904512);

  convert_kernel<<<2048, 256, 0, stream>>>(x, wq, wk, wv,
                                           xb, wqkb, wqkb + 262144, wvb);
  // [Q|K] = x * [Wq;Wk]^T : [16384x1024]
  gemm_nt_kernel<<<dim3(GS / 128, 1024 / 128), 256, 0, stream>>>(xb, wqkb, qk, 1024);
  // Vt[e][gs] = Wv * x^T : [512x16384]
  gemm_nt_kernel<<<dim3(DM / 128, GS / 128), 256, 0, stream>>>(wvb, xb, vt, GS);
  // fused attention
  attn_kernel<<<512, 256, 0, stream>>>(qk, vt, out);
}